// Round 13
// baseline (285.431 us; speedup 1.0000x reference)
//
#include <hip/hip_runtime.h>

typedef __attribute__((ext_vector_type(4))) float f32x4;
typedef __attribute__((ext_vector_type(4))) int   i32x4;

static constexpr int Kd = 4096, Nd = 16384, Md = 1024;
static constexpr int BK = 128;          // K-elems (i8) per tile
static constexpr int NT = Kd / BK;      // 32 K-tiles
static constexpr int BM = 128, BN = 256;

// ---------- helpers ----------

__device__ __forceinline__ void gload16(const char* g, char* l) {
    __builtin_amdgcn_global_load_lds(
        (const __attribute__((address_space(1))) void*)g,
        (__attribute__((address_space(3))) void*)l, 16, 0, 0);
}

__device__ __forceinline__ int pack4(int a, int b, int c, int d) {
    return (a & 255) | ((b & 255) << 8) | ((c & 255) << 16) | (d << 24);
}

// ---------- convert X: f32 [M][K] -> per-row absmax-scaled int8 ----------

__global__ __launch_bounds__(256) void convert_x_kernel(
    const float* __restrict__ x, char* __restrict__ xb, float* __restrict__ xs) {
    const int row = blockIdx.x;
    const int t   = threadIdx.x;
    const float* xr = x + (size_t)row * Kd;

    f32x4 v[4];
    float amax = 0.f;
    #pragma unroll
    for (int i = 0; i < 4; ++i) {
        v[i] = *(const f32x4*)(xr + t * 16 + i * 4);
        #pragma unroll
        for (int j = 0; j < 4; ++j) amax = fmaxf(amax, fabsf(v[i][j]));
    }
    #pragma unroll
    for (int off = 32; off; off >>= 1)
        amax = fmaxf(amax, __shfl_xor(amax, off));
    __shared__ float wmax[4];
    if ((t & 63) == 0) wmax[t >> 6] = amax;
    __syncthreads();
    amax = fmaxf(fmaxf(wmax[0], wmax[1]), fmaxf(wmax[2], wmax[3]));
    amax = fmaxf(amax, 1e-20f);

    const float inv = 127.0f / amax;
    i32x4 o;
    #pragma unroll
    for (int i = 0; i < 4; ++i) {
        int q[4];
        #pragma unroll
        for (int j = 0; j < 4; ++j) {
            int qi = __float2int_rn(v[i][j] * inv);
            qi = qi > 127 ? 127 : (qi < -127 ? -127 : qi);
            q[j] = qi;
        }
        o[i] = pack4(q[0], q[1], q[2], q[3]);
    }
    *(i32x4*)(xb + (size_t)row * Kd + t * 16) = o;
    if (t == 0) xs[row] = amax * (1.0f / 127.0f);
}

// ---------- single-pass 128x256 i8 GEMM from RAW int32 W ----------
// C[m,n] = sw[n]*xs[m] * sum_k xq[m,k]*w8[n,k] + bias[n], w8 = low byte of Wq.
// NO convert_w pass. 8 waves, N-SPLIT: wave w owns n-cols [w*32,+32), all
// 128 m -> per-CU B raw bytes/tile = 256 rows x 512 B = 128 KB, ZERO
// duplication (r9's fatal 16x fixed). acc 8mi x 2nj = 64 regs; af kk-batched
// 32; raw 2x32; bfp 16; ~196 total -> 2 waves/SIMD, no spill (r7/r8 fixed).
// A: i8 via LDS, r10's proven path (2 slots x 16 KiB, XOR swizzle inverse
// folded into gload source). B: raw int32 -> regs -> pack4 -> MFMA.
// Per-tile FIFO ledger (oldest left; waits audited incl. prologue/tail):
//  entry [bh1(t):8 in rawX]; bfp0 = packed bh0(t)
//  STAGE_A(t+1):2 ; LOAD bh0(t+1)->rawY:8  => [bh1:8, A:2, bh0':8]
//  READ_A(kk0) ; VMCNT(10) -> bh1(t) arrived ; PACK bfp1<-rawX
//  LGKM0 ; MFMA kk0 (bfp0) ; READ_A(kk1) ; LOAD bh1(t+1)->rawX:8
//  LGKM0 ; MFMA kk1 (bfp1)
//  VMCNT(8) -> A(t+1)+bh0' done ; PACK bfp0<-rawY ; BARRIER
// Tail t=NT-1: no stages/loads; VMCNT(0) before PACK bfp1.

#define BARRIER() asm volatile("s_barrier" ::: "memory")

#define LGKM0_FENCE() do {                                                     \
    asm volatile("s_waitcnt lgkmcnt(0)");                                      \
    __builtin_amdgcn_sched_barrier(0);                                         \
} while (0)

#define VMCNT(n) do {                                                          \
    asm volatile("s_waitcnt vmcnt(" #n ")" ::: "memory");                      \
    __builtin_amdgcn_sched_barrier(0);                                         \
} while (0)

// stage A tile (128 rows x 128 B) for kt into slot: 2 gload_lds/thread
#define STAGE_A2(slot, kt) do {                                                \
    _Pragma("unroll")                                                          \
    for (int i_ = 0; i_ < 2; ++i_) {                                           \
        char* lb_ = &LDSA[slot][i_ * 64 + w * 8][0];                           \
        gload16(Ab + (aRow0 + i_ * 64) * (size_t)Kd + (kt) * BK + gcol, lb_);  \
    }                                                                          \
    __builtin_amdgcn_sched_barrier(0);                                         \
} while (0)

// 8 dwordx4 raw int32 loads for kk-half (kkh) of tile kt -> buf[8]
// lane l: n-row = gn0 + w*32 + nj*16 + (l&15), k-ints kkh*64 + (l>>4)*16 + i*4
#define LOAD_BH(buf, kt, kkh) do {                                             \
    _Pragma("unroll")                                                          \
    for (int nj = 0; nj < 2; ++nj)                                             \
        _Pragma("unroll")                                                      \
        for (int i = 0; i < 4; ++i)                                            \
            buf[nj * 4 + i] = *(const i32x4*)(bW + (size_t)nj * 16 * Kd        \
                                              + (kt) * BK + (kkh) * 64 + i * 4);\
    __builtin_amdgcn_sched_barrier(0);                                         \
} while (0)

// pack 16 raw ints per nj -> one i32x4 of i8 (k ascending)
#define PACK_BF(bfp, buf) do {                                                 \
    _Pragma("unroll")                                                          \
    for (int nj = 0; nj < 2; ++nj)                                             \
        _Pragma("unroll")                                                      \
        for (int d = 0; d < 4; ++d)                                            \
            bfp[nj][d] = pack4(buf[nj * 4 + d][0], buf[nj * 4 + d][1],         \
                               buf[nj * 4 + d][2], buf[nj * 4 + d][3]);        \
} while (0)

// 8 ds_read_b128 -> af[8] for one kk-half
#define READ_A8(slot, kk) do {                                                 \
    const char* lA_ = &LDSA[slot][0][0];                                       \
    _Pragma("unroll")                                                          \
    for (int mi = 0; mi < 8; ++mi) {                                           \
        const int row_ = mi * 16 + lr;                                         \
        const int col_ = (l4 * 16 + (kk) * 64) ^ xorv;                         \
        af[mi] = *(const i32x4*)(lA_ + row_ * 128 + col_);                     \
    }                                                                          \
    __builtin_amdgcn_sched_barrier(0);                                         \
} while (0)

// 16 MFMA: mi 0..7 x nj 0..1, one kk-half
#define MFMA_G(BFP) do {                                                       \
    __builtin_amdgcn_s_setprio(1);                                             \
    _Pragma("unroll")                                                          \
    for (int mi = 0; mi < 8; ++mi)                                             \
        _Pragma("unroll")                                                      \
        for (int nj = 0; nj < 2; ++nj)                                         \
            acc[mi][nj] = __builtin_amdgcn_mfma_i32_16x16x64_i8(               \
                af[mi], BFP[nj], acc[mi][nj], 0, 0, 0);                        \
    __builtin_amdgcn_s_setprio(0);                                             \
} while (0)

#define TILE(slot, oslot, t) do {                                              \
    if ((t) + 1 < NT) {                                                        \
        STAGE_A2(oslot, (t) + 1);      /* [bh1:8, A:2] */                      \
        LOAD_BH(rawY, (t) + 1, 0);     /* [bh1:8, A:2, bh0':8] */              \
    }                                                                          \
    READ_A8(slot, 0);                                                          \
    if ((t) + 1 < NT) { VMCNT(10); } else { VMCNT(0); }  /* bh1(t) done */     \
    PACK_BF(bfp1, rawX);                                                       \
    LGKM0_FENCE();                                                             \
    MFMA_G(bfp0);                      /* kk=0 */                              \
    READ_A8(slot, 1);                                                          \
    if ((t) + 1 < NT) LOAD_BH(rawX, (t) + 1, 1);  /* [A:2, bh0':8, bh1':8] */  \
    LGKM0_FENCE();                                                             \
    MFMA_G(bfp1);                      /* kk=1 */                              \
    if ((t) + 1 < NT) {                                                        \
        VMCNT(8);                      /* A(t+1)+bh0' retired */               \
        PACK_BF(bfp0, rawY);                                                   \
        BARRIER();                                                             \
    }                                                                          \
} while (0)

__global__ __launch_bounds__(512, 2) void gemmr_kernel(
    const char* __restrict__ Ab,        // xq [M][K] i8
    const int*  __restrict__ Wq,        // weight_quant [N][K] int32 (RAW input)
    const float* __restrict__ sw,       // per-n weight scale
    const float* __restrict__ xs,       // per-m activation scale
    const float* __restrict__ bias,
    float* __restrict__ C) {

    __shared__ __align__(16) char LDSA[2][128][128];   // 32 KiB, A only

    const int tid = threadIdx.x;
    const int l   = tid & 63;
    const int w   = tid >> 6;          // wave 0..7 (n slice)
    const int lr  = l & 15;
    const int l4  = l >> 4;            // 0..3
    const int xorv = (lr & 7) << 4;

    // bijective XCD swizzle (512 wg, 64/XCD), m-fastest: the 8 m-blocks
    // sharing an n-panel run concurrently on one XCD -> W panel L2-windowed
    const int orig = blockIdx.x;
    const int work = (orig & 7) * 64 + (orig >> 3);
    const int gm0 = (work & 7) * BM;
    const int gn0 = (work >> 3) * BN;

    // A staging source geometry (inverse of read-side XOR swizzle), bytes
    const int g_log = (l & 7) ^ ((l >> 3) & 7);
    const int gcol  = g_log * 16;
    const size_t aRow0 = (size_t)(gm0 + w * 8 + (l >> 3));

    // B raw int32 base: n-row gn0 + w*32 + lr, k-int offset l4*16 (int units)
    const int* bW = Wq + (size_t)(gn0 + w * 32 + lr) * Kd + l4 * 16;

    i32x4 af[8];                       // A frags, one kk-half, 32 regs
    i32x4 rawX[8], rawY[8];            // raw int32 halves, 32+32 regs
    i32x4 bfp0[2], bfp1[2];            // packed i8 B frags, 8+8 regs

    i32x4 acc[8][2];                   // 64 regs
    #pragma unroll
    for (int i = 0; i < 8; ++i)
        #pragma unroll
        for (int j = 0; j < 2; ++j) {
            i32x4 z = {0, 0, 0, 0};
            acc[i][j] = z;
        }

    // prologue: A(0) staged; bh0(0)+bh1(0) issued; bfp0 packed
    STAGE_A2(0, 0);                    // [A:2]
    LOAD_BH(rawY, 0, 0);               // [A:2, bh0:8]
    LOAD_BH(rawX, 0, 1);               // [A:2, bh0:8, bh1:8]
    VMCNT(8);                          // A(0) + bh0(0) retired
    PACK_BF(bfp0, rawY);
    BARRIER();

    #pragma unroll 1
    for (int tt = 0; tt < NT / 2; ++tt) {
        TILE(0, 1, 2 * tt);
        TILE(1, 0, 2 * tt + 1);
    }

    // epilogue: C = sw[n]*xs[m]*acc + bias[n]
    // C/D layout (dtype-independent): col = lane&15 (n), row = (lane>>4)*4+reg
    #pragma unroll
    for (int nj = 0; nj < 2; ++nj) {
        const int gn = gn0 + w * 32 + nj * 16 + lr;
        const float sc = sw[gn];
        const float bi = bias[gn];
        #pragma unroll
        for (int mi = 0; mi < 8; ++mi) {
            const int gm = gm0 + mi * 16 + l4 * 4;
            #pragma unroll
            for (int r = 0; r < 4; ++r)
                C[(size_t)(gm + r) * Nd + gn] =
                    (float)acc[mi][nj][r] * (sc * xs[gm + r]) + bi;
        }
    }
}

// ---------- fallback (ws too small): slow but correct ----------

__global__ __launch_bounds__(256) void naive_kernel(
    const float* __restrict__ x, const int* __restrict__ wq,
    const float* __restrict__ scale, const float* __restrict__ bias,
    float* __restrict__ out) {
    const int n = blockIdx.x * 256 + threadIdx.x;
    const int m = blockIdx.y;
    if (n >= Nd) return;
    const float* xr = x + (size_t)m * Kd;
    const int*   wr = wq + (size_t)n * Kd;
    float s = 0.f;
    for (int k = 0; k < Kd; ++k) s += xr[k] * (float)wr[k];
    out[(size_t)m * Nd + n] = s * scale[n] + bias[n];
}

// ---------- launch ----------

extern "C" void kernel_launch(void* const* d_in, const int* in_sizes, int n_in,
                              void* d_out, int out_size, void* d_ws, size_t ws_size,
                              hipStream_t stream) {
    const float* x     = (const float*)d_in[0];
    const int*   wq    = (const int*)d_in[1];
    const float* scale = (const float*)d_in[2];
    const float* bias  = (const float*)d_in[3];
    float* out = (float*)d_out;

    const size_t x_bytes = (size_t)Md * Kd;              // 4 MiB (i8)
    const size_t s_bytes = (size_t)Md * sizeof(float);   // 4 KiB
    if (ws_size >= x_bytes + s_bytes && d_ws != nullptr) {
        char*  xb = (char*)d_ws;
        float* xs = (float*)(xb + x_bytes);
        convert_x_kernel<<<Md, 256, 0, stream>>>(x, xb, xs);
        const int nwg = (Md / BM) * (Nd / BN);           // 512
        gemmr_kernel<<<nwg, 512, 0, stream>>>(xb, wq, scale, xs, bias, out);
    } else {
        dim3 grid(Nd / 256, Md);
        naive_kernel<<<grid, 256, 0, stream>>>(x, wq, scale, bias, out);
    }
}